// Round 3
// baseline (1464.699 us; speedup 1.0000x reference)
//
#include <hip/hip_runtime.h>

#define N_USERS 100000
#define N_ITEMS 50000
#define DIM     64
#define N_NODES (N_USERS + N_ITEMS + 1)   /* 150001 */
#define N_EDGES 4800000

static constexpr long long NF = (long long)N_NODES * DIM;   // 9,600,064 floats per tensor

// ------------------- scan geometry -------------------
#define SCAN_T      256
#define SCAN_ITEMS  8
#define SCAN_CHUNK  (SCAN_T * SCAN_ITEMS)                    /* 2048 */
#define SCAN_NBLK   ((N_NODES + SCAN_CHUNK - 1) / SCAN_CHUNK) /* 74 */

// ------------------- bucket geometry -------------------
// 64 rows per bucket; mean fill = 64*32 = 2048 edges, cap 4096 (~45 sigma
// for uniform rows). Oversized buckets fall back to direct scatter (big[]).
#define ROWS_PER_BKT 64
#define BKT_SHIFT    6
#define N_BKT        ((N_NODES + ROWS_PER_BKT - 1) >> BKT_SHIFT)   /* 2344 */
#define BUCKET_CAP   4096

// ---------------------------------------------------------------------------
// zero-fill for deg (graph-capture-safe, no hipMemsetAsync)
// ---------------------------------------------------------------------------
__global__ void zero_kernel(int* __restrict__ p, int n) {
    int i = blockIdx.x * blockDim.x + threadIdx.x;
    if (i < n) p[i] = 0;
}

// ---------------------------------------------------------------------------
// ego = concat(user_emb, item_emb)  (float4-vectorized)
// ---------------------------------------------------------------------------
__global__ void concat_kernel(const float4* __restrict__ user,
                              const float4* __restrict__ item,
                              float4* __restrict__ ego) {
    int i = blockIdx.x * blockDim.x + threadIdx.x;
    const int userF4 = N_USERS * DIM / 4;
    const int totF4  = (int)(NF / 4);
    if (i < userF4)      ego[i] = user[i];
    else if (i < totF4)  ego[i] = item[i - userF4];
}

// ---------------------------------------------------------------------------
// CSR build step 1: histogram of rows
// ---------------------------------------------------------------------------
__global__ void hist_kernel(const int* __restrict__ rows, int* __restrict__ deg) {
    int e = blockIdx.x * blockDim.x + threadIdx.x;
    if (e < N_EDGES) atomicAdd(&deg[rows[e]], 1);
}

// ---------------------------------------------------------------------------
// CSR build step 2a: per-block partial sums of deg (74 blocks x 2048 elems)
// ---------------------------------------------------------------------------
__global__ void __launch_bounds__(SCAN_T)
scan_a_kernel(const int* __restrict__ deg, int* __restrict__ bsum) {
    __shared__ int lds[SCAN_T];
    int b = blockIdx.x, t = threadIdx.x;
    int base = b * SCAN_CHUNK + t * SCAN_ITEMS;
    int s = 0;
    #pragma unroll
    for (int i = 0; i < SCAN_ITEMS; ++i) {
        int idx = base + i;
        s += (idx < N_NODES) ? deg[idx] : 0;
    }
    lds[t] = s;
    __syncthreads();
    for (int off = SCAN_T / 2; off > 0; off >>= 1) {
        if (t < off) lds[t] += lds[t + off];
        __syncthreads();
    }
    if (t == 0) bsum[b] = lds[0];
}

// ---------------------------------------------------------------------------
// CSR build step 2b: exclusive scan of the 74 block sums (one tiny block)
// ---------------------------------------------------------------------------
__global__ void __launch_bounds__(128)
scan_b_kernel(const int* __restrict__ bsum, int* __restrict__ boff) {
    __shared__ int lds[128];
    int t = threadIdx.x;
    lds[t] = (t < SCAN_NBLK) ? bsum[t] : 0;
    __syncthreads();
    for (int off = 1; off < 128; off <<= 1) {
        int x = lds[t];
        int y = (t >= off) ? lds[t - off] : 0;
        __syncthreads();
        lds[t] = x + y;
        __syncthreads();
    }
    if (t < SCAN_NBLK) boff[t] = (t == 0) ? 0 : lds[t - 1];
}

// ---------------------------------------------------------------------------
// CSR build step 2c: block-local exclusive scan + block offset -> row_ptr,cursor
// ---------------------------------------------------------------------------
__global__ void __launch_bounds__(SCAN_T)
scan_c_kernel(const int* __restrict__ deg, const int* __restrict__ boff,
              int* __restrict__ row_ptr, int* __restrict__ cursor) {
    __shared__ int lds[SCAN_T];
    int b = blockIdx.x, t = threadIdx.x;
    int base = b * SCAN_CHUNK + t * SCAN_ITEMS;
    int v[SCAN_ITEMS];
    int s = 0;
    #pragma unroll
    for (int i = 0; i < SCAN_ITEMS; ++i) {
        int idx = base + i;
        int d = (idx < N_NODES) ? deg[idx] : 0;
        v[i] = s;                 // exclusive prefix within thread
        s += d;
    }
    lds[t] = s;
    __syncthreads();
    // Hillis-Steele inclusive scan over the 256 thread sums
    for (int off = 1; off < SCAN_T; off <<= 1) {
        int x = lds[t];
        int y = (t >= off) ? lds[t - off] : 0;
        __syncthreads();
        lds[t] = x + y;
        __syncthreads();
    }
    int toff = ((t == 0) ? 0 : lds[t - 1]) + boff[b];
    #pragma unroll
    for (int i = 0; i < SCAN_ITEMS; ++i) {
        int idx = base + i;
        if (idx < N_NODES) {
            int val = v[i] + toff;
            row_ptr[idx] = val;
            cursor[idx]  = val;
        }
    }
    if (b == 0 && t == 0) row_ptr[N_NODES] = N_EDGES;
}

// ---------------------------------------------------------------------------
// bucket init: bucket cursor = row_ptr at bucket start; flag oversize buckets
// ---------------------------------------------------------------------------
__global__ void bucket_init_kernel(const int* __restrict__ row_ptr,
                                   int* __restrict__ bcur,
                                   int* __restrict__ big) {
    int b = blockIdx.x * blockDim.x + threadIdx.x;
    if (b < N_BKT) {
        int lo = b << BKT_SHIFT;
        int hi = lo + ROWS_PER_BKT;
        if (hi > N_NODES) hi = N_NODES;
        int s = row_ptr[lo];
        int e = row_ptr[hi];
        bcur[b] = s;
        big[b]  = (e - s > BUCKET_CAP) ? 1 : 0;
    }
}

// ---------------------------------------------------------------------------
// scatter phase 1: append edge to its 64-row bucket region (sequential
// positions via per-bucket cursor -> stores coalesce in L2, ~1x write amp).
// Packed entry: word0 = (row_local<<18) | col  (6+18 bits), word1 = val bits.
// Oversized buckets (never for uniform rows) get direct final placement.
// ---------------------------------------------------------------------------
__global__ void bucket_scatter_kernel(const int* __restrict__ rows,
                                      const int* __restrict__ cols,
                                      const float* __restrict__ vals,
                                      const int* __restrict__ big,
                                      int* __restrict__ bcur,
                                      int* __restrict__ cursor,
                                      uint2* __restrict__ edges) {
    int e = blockIdx.x * blockDim.x + threadIdx.x;
    if (e >= N_EDGES) return;
    int r = rows[e];
    unsigned c = (unsigned)cols[e];
    unsigned v = __float_as_uint(vals[e]);
    int b = r >> BKT_SHIFT;
    if (!big[b]) {
        int p = atomicAdd(&bcur[b], 1);
        edges[p] = make_uint2(((unsigned)(r & (ROWS_PER_BKT - 1)) << 18) | c, v);
    } else {
        int p = atomicAdd(&cursor[r], 1);
        edges[p] = make_uint2(c, v);
    }
}

// ---------------------------------------------------------------------------
// scatter phase 2: in-place permutation within each bucket's interval.
// Bucket's packed region and its final CSR region are the SAME interval
// (both derived from row_ptr), so: load to LDS, barrier, scatter back with
// LDS-atomic row cursors. All traffic stays in a just-read L2 interval.
// ---------------------------------------------------------------------------
__global__ void __launch_bounds__(256)
csr_place_kernel(const int* __restrict__ row_ptr,
                 const int* __restrict__ big,
                 uint2* __restrict__ edges) {
    __shared__ uint2 lds_e[BUCKET_CAP];
    __shared__ int   lds_cur[ROWS_PER_BKT];
    int b = blockIdx.x;
    if (big[b]) return;                      // already placed by phase 1
    int r0 = b << BKT_SHIFT;
    int hi = r0 + ROWS_PER_BKT;
    if (hi > N_NODES) hi = N_NODES;
    int nrows = hi - r0;
    int base  = row_ptr[r0];
    int n     = row_ptr[hi] - base;
    int t = threadIdx.x;
    for (int i = t; i < n; i += 256) lds_e[i] = edges[base + i];
    if (t < nrows) lds_cur[t] = row_ptr[r0 + t];
    __syncthreads();
    for (int i = t; i < n; i += 256) {
        uint2 ed = lds_e[i];
        int p = atomicAdd(&lds_cur[ed.x >> 18], 1);
        edges[p] = make_uint2(ed.x & 0x3FFFFu, ed.y);
    }
}

// ---------------------------------------------------------------------------
// CSR SpMM: one wave per row; lane d owns dim d. 8 independent load->FMA
// chains per iteration (avg degree 32 -> 4 main-loop iterations).
// ---------------------------------------------------------------------------
__global__ void __launch_bounds__(256)
spmm_csr_kernel(const int* __restrict__ row_ptr,
                const uint2* __restrict__ edges,
                const float* __restrict__ hin,
                float* __restrict__ hout) {
    int wave = (blockIdx.x * blockDim.x + threadIdx.x) >> 6;
    int lane = threadIdx.x & 63;
    if (wave >= N_NODES) return;
    int start = row_ptr[wave];
    int end   = row_ptr[wave + 1];
    float a0 = 0.f, a1 = 0.f, a2 = 0.f, a3 = 0.f;
    float a4 = 0.f, a5 = 0.f, a6 = 0.f, a7 = 0.f;
    int e = start;
    for (; e + 8 <= end; e += 8) {
        uint2 e0 = edges[e],     e1 = edges[e + 1], e2 = edges[e + 2], e3 = edges[e + 3];
        uint2 e4 = edges[e + 4], e5 = edges[e + 5], e6 = edges[e + 6], e7 = edges[e + 7];
        a0 += __uint_as_float(e0.y) * hin[(int)e0.x * DIM + lane];
        a1 += __uint_as_float(e1.y) * hin[(int)e1.x * DIM + lane];
        a2 += __uint_as_float(e2.y) * hin[(int)e2.x * DIM + lane];
        a3 += __uint_as_float(e3.y) * hin[(int)e3.x * DIM + lane];
        a4 += __uint_as_float(e4.y) * hin[(int)e4.x * DIM + lane];
        a5 += __uint_as_float(e5.y) * hin[(int)e5.x * DIM + lane];
        a6 += __uint_as_float(e6.y) * hin[(int)e6.x * DIM + lane];
        a7 += __uint_as_float(e7.y) * hin[(int)e7.x * DIM + lane];
    }
    for (; e + 4 <= end; e += 4) {
        uint2 e0 = edges[e], e1 = edges[e + 1], e2 = edges[e + 2], e3 = edges[e + 3];
        a0 += __uint_as_float(e0.y) * hin[(int)e0.x * DIM + lane];
        a1 += __uint_as_float(e1.y) * hin[(int)e1.x * DIM + lane];
        a2 += __uint_as_float(e2.y) * hin[(int)e2.x * DIM + lane];
        a3 += __uint_as_float(e3.y) * hin[(int)e3.x * DIM + lane];
    }
    for (; e < end; ++e) {
        uint2 ed = edges[e];
        a0 += __uint_as_float(ed.y) * hin[(int)ed.x * DIM + lane];
    }
    hout[wave * DIM + lane] = ((a0 + a1) + (a2 + a3)) + ((a4 + a5) + (a6 + a7));
}

// ---------------------------------------------------------------------------
// CSR SpMM (last layer) fused with h_sum = ego + h1 + h2 + h3
// ---------------------------------------------------------------------------
__global__ void __launch_bounds__(256)
spmm_csr_fused_kernel(const int* __restrict__ row_ptr,
                      const uint2* __restrict__ edges,
                      const float* __restrict__ h2,      // gather source
                      const float* __restrict__ ego,
                      const float* __restrict__ h1,
                      float* __restrict__ h3,
                      float* __restrict__ hsum) {
    int wave = (blockIdx.x * blockDim.x + threadIdx.x) >> 6;
    int lane = threadIdx.x & 63;
    if (wave >= N_NODES) return;
    int start = row_ptr[wave];
    int end   = row_ptr[wave + 1];
    float a0 = 0.f, a1 = 0.f, a2 = 0.f, a3 = 0.f;
    float a4 = 0.f, a5 = 0.f, a6 = 0.f, a7 = 0.f;
    int e = start;
    for (; e + 8 <= end; e += 8) {
        uint2 e0 = edges[e],     e1 = edges[e + 1], e2 = edges[e + 2], e3 = edges[e + 3];
        uint2 e4 = edges[e + 4], e5 = edges[e + 5], e6 = edges[e + 6], e7 = edges[e + 7];
        a0 += __uint_as_float(e0.y) * h2[(int)e0.x * DIM + lane];
        a1 += __uint_as_float(e1.y) * h2[(int)e1.x * DIM + lane];
        a2 += __uint_as_float(e2.y) * h2[(int)e2.x * DIM + lane];
        a3 += __uint_as_float(e3.y) * h2[(int)e3.x * DIM + lane];
        a4 += __uint_as_float(e4.y) * h2[(int)e4.x * DIM + lane];
        a5 += __uint_as_float(e5.y) * h2[(int)e5.x * DIM + lane];
        a6 += __uint_as_float(e6.y) * h2[(int)e6.x * DIM + lane];
        a7 += __uint_as_float(e7.y) * h2[(int)e7.x * DIM + lane];
    }
    for (; e + 4 <= end; e += 4) {
        uint2 e0 = edges[e], e1 = edges[e + 1], e2 = edges[e + 2], e3 = edges[e + 3];
        a0 += __uint_as_float(e0.y) * h2[(int)e0.x * DIM + lane];
        a1 += __uint_as_float(e1.y) * h2[(int)e1.x * DIM + lane];
        a2 += __uint_as_float(e2.y) * h2[(int)e2.x * DIM + lane];
        a3 += __uint_as_float(e3.y) * h2[(int)e3.x * DIM + lane];
    }
    for (; e < end; ++e) {
        uint2 ed = edges[e];
        a0 += __uint_as_float(ed.y) * h2[(int)ed.x * DIM + lane];
    }
    float acc = ((a0 + a1) + (a2 + a3)) + ((a4 + a5) + (a6 + a7));
    int o = wave * DIM + lane;
    h3[o]   = acc;
    hsum[o] = ego[o] + h1[o] + h2[o] + acc;
}

// ---------------------------------------------------------------------------
// Fallback SpMM via fp32 atomics (used only if ws_size too small for CSR)
// ---------------------------------------------------------------------------
__global__ void spmm_atomic_kernel(const int* __restrict__ rows,
                                   const int* __restrict__ cols,
                                   const float* __restrict__ vals,
                                   const float* __restrict__ hin,
                                   float* __restrict__ hout) {
    int e = blockIdx.x * 4 + (threadIdx.x >> 6);
    int d = threadIdx.x & 63;
    if (e < N_EDGES) {
        atomicAdd(&hout[rows[e] * DIM + d], vals[e] * hin[cols[e] * DIM + d]);
    }
}

__global__ void zero_f_kernel(float* __restrict__ p, long long n) {
    long long i = (long long)blockIdx.x * blockDim.x + threadIdx.x;
    if (i < n) p[i] = 0.f;
}

__global__ void sum_kernel(const float4* __restrict__ a,
                           const float4* __restrict__ b,
                           const float4* __restrict__ c,
                           const float4* __restrict__ d,
                           float4* __restrict__ out) {
    int i = blockIdx.x * blockDim.x + threadIdx.x;
    if (i < (int)(NF / 4)) {
        float4 x = a[i], y = b[i], z = c[i], w = d[i];
        out[i] = make_float4(x.x + y.x + z.x + w.x,
                             x.y + y.y + z.y + w.y,
                             x.z + y.z + z.z + w.z,
                             x.w + y.w + z.w + w.w);
    }
}

extern "C" void kernel_launch(void* const* d_in, const int* in_sizes, int n_in,
                              void* d_out, int out_size, void* d_ws, size_t ws_size,
                              hipStream_t stream) {
    const float* user = (const float*)d_in[0];
    const float* item = (const float*)d_in[1];
    const float* vals = (const float*)d_in[2];
    const int*   rows = (const int*)d_in[3];
    const int*   cols = (const int*)d_in[4];

    float* out  = (float*)d_out;
    float* hsum = out;
    float* ego  = out + NF;
    float* h1   = out + 2 * NF;
    float* h2   = out + 3 * NF;
    float* h3   = out + 4 * NF;

    const int totF4 = (int)(NF / 4);

    concat_kernel<<<(totF4 + 255) / 256, 256, 0, stream>>>(
        (const float4*)user, (const float4*)item, (float4*)ego);

    // workspace layout: edges first (8B aligned), then int arrays
    const size_t nInt = (size_t)(N_NODES + 2);
    size_t need = (size_t)N_EDGES * 8
                + (3 * nInt + 2 * (size_t)N_BKT + 2 * 128) * 4;   // ~40.2 MB

    if (ws_size >= need) {
        uint2* edges   = (uint2*)d_ws;
        int*   deg     = (int*)(edges + N_EDGES);
        int*   row_ptr = deg + nInt;
        int*   cursor  = row_ptr + nInt;
        int*   bcur    = cursor + nInt;
        int*   big     = bcur + N_BKT;
        int*   bsum    = big + N_BKT;
        int*   boff    = bsum + 128;

        zero_kernel<<<(N_NODES + 255) / 256, 256, 0, stream>>>(deg, N_NODES);
        hist_kernel<<<(N_EDGES + 255) / 256, 256, 0, stream>>>(rows, deg);
        scan_a_kernel<<<SCAN_NBLK, SCAN_T, 0, stream>>>(deg, bsum);
        scan_b_kernel<<<1, 128, 0, stream>>>(bsum, boff);
        scan_c_kernel<<<SCAN_NBLK, SCAN_T, 0, stream>>>(deg, boff, row_ptr, cursor);
        bucket_init_kernel<<<(N_BKT + 255) / 256, 256, 0, stream>>>(row_ptr, bcur, big);
        bucket_scatter_kernel<<<(N_EDGES + 255) / 256, 256, 0, stream>>>(
            rows, cols, vals, big, bcur, cursor, edges);
        csr_place_kernel<<<N_BKT, 256, 0, stream>>>(row_ptr, big, edges);

        const int spmmBlocks = (N_NODES * 64 + 255) / 256;  // 1 wave per row
        spmm_csr_kernel<<<spmmBlocks, 256, 0, stream>>>(row_ptr, edges, ego, h1);
        spmm_csr_kernel<<<spmmBlocks, 256, 0, stream>>>(row_ptr, edges, h1,  h2);
        spmm_csr_fused_kernel<<<spmmBlocks, 256, 0, stream>>>(
            row_ptr, edges, h2, ego, h1, h3, hsum);
    } else {
        const long long nz = 3 * NF;
        zero_f_kernel<<<(int)((nz + 255) / 256), 256, 0, stream>>>(h1, nz);
        const int ablocks = (N_EDGES + 3) / 4;
        spmm_atomic_kernel<<<ablocks, 256, 0, stream>>>(rows, cols, vals, ego, h1);
        spmm_atomic_kernel<<<ablocks, 256, 0, stream>>>(rows, cols, vals, h1,  h2);
        spmm_atomic_kernel<<<ablocks, 256, 0, stream>>>(rows, cols, vals, h2,  h3);
        sum_kernel<<<(totF4 + 255) / 256, 256, 0, stream>>>(
            (const float4*)ego, (const float4*)h1, (const float4*)h2, (const float4*)h3,
            (float4*)hsum);
    }
}

// Round 4
// 882.454 us; speedup vs baseline: 1.6598x; 1.6598x over previous
//
#include <hip/hip_runtime.h>

#define N_USERS 100000
#define N_ITEMS 50000
#define DIM     64
#define N_NODES (N_USERS + N_ITEMS + 1)   /* 150001 */
#define N_EDGES 4800000

static constexpr long long NF = (long long)N_NODES * DIM;   // 9,600,064 floats per tensor

// ------------------- coarse-bucket counting-sort geometry -------------------
#define NCB      256                       /* coarse buckets                  */
#define CB_ROWS  586                       /* rows per bucket: 586*256=150016 */
#define CB_CAP   24576                     /* slots per bucket (mean 18750)   */
#define BCUR_PAD 16                        /* bcur stride in ints (64B lines) */
#define OVF_CAP  65536                     /* overflow list capacity          */
#define CHUNK_E  8192                      /* edges per binA workgroup        */
#define BINA_T   256
#define BINA_BLK ((N_EDGES + CHUNK_E - 1) / CHUNK_E)   /* 586 */
#define PB_T     1024

// ---------------------------------------------------------------------------
// ego = concat(user_emb, item_emb)  (float4-vectorized)
// ---------------------------------------------------------------------------
__global__ void concat_kernel(const float4* __restrict__ user,
                              const float4* __restrict__ item,
                              float4* __restrict__ ego) {
    int i = blockIdx.x * blockDim.x + threadIdx.x;
    const int userF4 = N_USERS * DIM / 4;
    const int totF4  = (int)(NF / 4);
    if (i < userF4)      ego[i] = user[i];
    else if (i < totF4)  ego[i] = item[i - userF4];
}

// ---------------------------------------------------------------------------
// build init: bucket cursors at fixed region bases; clear overflow count
// ---------------------------------------------------------------------------
__global__ void build_init_kernel(int* __restrict__ bcur, int* __restrict__ ovf_cnt) {
    int t = blockIdx.x * blockDim.x + threadIdx.x;
    if (t < NCB) bcur[t * BCUR_PAD] = t * CB_CAP;
    if (t == 0) *ovf_cnt = 0;
}

// ---------------------------------------------------------------------------
// binA: coarse binning. Per 8192-edge chunk: LDS histogram over 256 buckets,
// ONE padded global atomic per (chunk,bucket) to reserve a contiguous range,
// then write packed (row_local<<18 | col, val) into the bucket region.
// Runs are ~32 consecutive entries written by one CU -> lines merge in its L2.
// Global atomics: 150k total, 64B-strided counters -> no same-line serializing.
// ---------------------------------------------------------------------------
__global__ void __launch_bounds__(BINA_T)
binA_kernel(const int* __restrict__ rows, const int* __restrict__ cols,
            const float* __restrict__ vals,
            int* __restrict__ bcur, int* __restrict__ ovf_cnt,
            uint4* __restrict__ ovf, uint2* __restrict__ tmp) {
    __shared__ int hist[NCB];
    __shared__ int gbase[NCB];
    __shared__ int offs[NCB];
    int t = threadIdx.x;
    int base = blockIdx.x * CHUNK_E;
    int nend = N_EDGES - base; if (nend > CHUNK_E) nend = CHUNK_E;
    hist[t] = 0;
    __syncthreads();
    for (int i = t; i < nend; i += BINA_T) {
        int r = rows[base + i];
        atomicAdd(&hist[r / CB_ROWS], 1);
    }
    __syncthreads();
    int h = hist[t];
    gbase[t] = (h > 0) ? atomicAdd(&bcur[t * BCUR_PAD], h) : 0;
    offs[t] = 0;
    __syncthreads();
    for (int i = t; i < nend; i += BINA_T) {
        int e = base + i;
        int r = rows[e];
        unsigned c = (unsigned)cols[e];
        unsigned v = __float_as_uint(vals[e]);
        int b = r / CB_ROWS;
        int o = atomicAdd(&offs[b], 1);
        int p = gbase[b] + o;
        if (p < (b + 1) * CB_CAP) {
            tmp[p] = make_uint2(((unsigned)(r - b * CB_ROWS) << 18) | c, v);
        } else {                                   // statistically impossible
            int ov = atomicAdd(ovf_cnt, 1);
            if (ov < OVF_CAP) ovf[ov] = make_uint4((unsigned)r, c, v, 0u);
        }
    }
}

// ---------------------------------------------------------------------------
// cb_scan: bucket sizes -> exclusive scan -> csr_base. Replaces the old
// hist + 3-kernel scan. Also accounts (never-occurring) overflow edges.
// ---------------------------------------------------------------------------
__global__ void __launch_bounds__(NCB)
cb_scan_kernel(const int* __restrict__ bcur, const int* __restrict__ ovf_cnt,
               const uint4* __restrict__ ovf,
               int* __restrict__ stored, int* __restrict__ csr_base,
               int* __restrict__ row_ptr) {
    __shared__ int lds[NCB];
    __shared__ int oh[NCB];
    int t = threadIdx.x;
    int st = bcur[t * BCUR_PAD] - t * CB_CAP;
    if (st > CB_CAP) st = CB_CAP;
    stored[t] = st;
    oh[t] = 0;
    __syncthreads();
    int nov = *ovf_cnt; if (nov > OVF_CAP) nov = OVF_CAP;
    for (int i = t; i < nov; i += NCB) atomicAdd(&oh[(int)ovf[i].x / CB_ROWS], 1);
    __syncthreads();
    lds[t] = st + oh[t];
    __syncthreads();
    for (int off = 1; off < NCB; off <<= 1) {
        int x = lds[t];
        int y = (t >= off) ? lds[t - off] : 0;
        __syncthreads();
        lds[t] = x + y;
        __syncthreads();
    }
    csr_base[t] = (t == 0) ? 0 : lds[t - 1];
    if (t == 0) { csr_base[NCB] = lds[NCB - 1]; row_ptr[N_NODES] = N_EDGES; }
}

// ---------------------------------------------------------------------------
// passB: one workgroup per coarse bucket. LDS row-degree count -> LDS scan ->
// row_ptr write -> scatter the bucket's tmp interval into final CSR order
// using LDS-only cursors. All random writes confined to a ~150KB interval
// touched by ONE CU -> full-line writebacks from its L2. Zero global atomics.
// ---------------------------------------------------------------------------
__global__ void __launch_bounds__(PB_T)
passB_kernel(const int* __restrict__ stored, const int* __restrict__ csr_base,
             const int* __restrict__ ovf_cnt, const uint4* __restrict__ ovf,
             const uint2* __restrict__ tmp,
             uint2* __restrict__ edges, int* __restrict__ row_ptr) {
    __shared__ int sdeg[PB_T];
    __shared__ int scur[CB_ROWS];
    int b = blockIdx.x, t = threadIdx.x;
    int n = stored[b];
    const uint2* tb = tmp + (long long)b * CB_CAP;
    sdeg[t] = 0;
    __syncthreads();
    for (int i = t; i < n; i += PB_T)
        atomicAdd(&sdeg[tb[i].x >> 18], 1);
    int nov = *ovf_cnt; if (nov > OVF_CAP) nov = OVF_CAP;
    if (nov > 0) {
        for (int i = t; i < nov; i += PB_T) {
            int r = (int)ovf[i].x;
            if (r / CB_ROWS == b) atomicAdd(&sdeg[r - b * CB_ROWS], 1);
        }
    }
    __syncthreads();
    for (int off = 1; off < PB_T; off <<= 1) {       // inclusive scan
        int x = sdeg[t];
        int y = (t >= off) ? sdeg[t - off] : 0;
        __syncthreads();
        sdeg[t] = x + y;
        __syncthreads();
    }
    int cb = csr_base[b];
    int excl = (t == 0) ? 0 : sdeg[t - 1];
    int gr = b * CB_ROWS + t;
    if (t < CB_ROWS && gr < N_NODES) {
        row_ptr[gr] = cb + excl;
        scur[t] = cb + excl;
    }
    __syncthreads();
    for (int i = t; i < n; i += PB_T) {
        uint2 ed = tb[i];
        int p = atomicAdd(&scur[ed.x >> 18], 1);
        edges[p] = make_uint2(ed.x & 0x3FFFFu, ed.y);
    }
    if (nov > 0 && t == 0) {
        for (int i = 0; i < nov; ++i) {
            int r = (int)ovf[i].x;
            if (r / CB_ROWS == b) {
                int p = atomicAdd(&scur[r - b * CB_ROWS], 1);
                edges[p] = make_uint2(ovf[i].y, ovf[i].z);
            }
        }
    }
}

// ---------------------------------------------------------------------------
// CSR SpMM: one wave per row; lane d owns dim d. 8 independent load->FMA
// chains per iteration (avg degree 32 -> 4 main-loop iterations).
// ---------------------------------------------------------------------------
__global__ void __launch_bounds__(256)
spmm_csr_kernel(const int* __restrict__ row_ptr,
                const uint2* __restrict__ edges,
                const float* __restrict__ hin,
                float* __restrict__ hout) {
    int wave = (blockIdx.x * blockDim.x + threadIdx.x) >> 6;
    int lane = threadIdx.x & 63;
    if (wave >= N_NODES) return;
    int start = row_ptr[wave];
    int end   = row_ptr[wave + 1];
    float a0 = 0.f, a1 = 0.f, a2 = 0.f, a3 = 0.f;
    float a4 = 0.f, a5 = 0.f, a6 = 0.f, a7 = 0.f;
    int e = start;
    for (; e + 8 <= end; e += 8) {
        uint2 e0 = edges[e],     e1 = edges[e + 1], e2 = edges[e + 2], e3 = edges[e + 3];
        uint2 e4 = edges[e + 4], e5 = edges[e + 5], e6 = edges[e + 6], e7 = edges[e + 7];
        a0 += __uint_as_float(e0.y) * hin[(int)e0.x * DIM + lane];
        a1 += __uint_as_float(e1.y) * hin[(int)e1.x * DIM + lane];
        a2 += __uint_as_float(e2.y) * hin[(int)e2.x * DIM + lane];
        a3 += __uint_as_float(e3.y) * hin[(int)e3.x * DIM + lane];
        a4 += __uint_as_float(e4.y) * hin[(int)e4.x * DIM + lane];
        a5 += __uint_as_float(e5.y) * hin[(int)e5.x * DIM + lane];
        a6 += __uint_as_float(e6.y) * hin[(int)e6.x * DIM + lane];
        a7 += __uint_as_float(e7.y) * hin[(int)e7.x * DIM + lane];
    }
    for (; e + 4 <= end; e += 4) {
        uint2 e0 = edges[e], e1 = edges[e + 1], e2 = edges[e + 2], e3 = edges[e + 3];
        a0 += __uint_as_float(e0.y) * hin[(int)e0.x * DIM + lane];
        a1 += __uint_as_float(e1.y) * hin[(int)e1.x * DIM + lane];
        a2 += __uint_as_float(e2.y) * hin[(int)e2.x * DIM + lane];
        a3 += __uint_as_float(e3.y) * hin[(int)e3.x * DIM + lane];
    }
    for (; e < end; ++e) {
        uint2 ed = edges[e];
        a0 += __uint_as_float(ed.y) * hin[(int)ed.x * DIM + lane];
    }
    hout[wave * DIM + lane] = ((a0 + a1) + (a2 + a3)) + ((a4 + a5) + (a6 + a7));
}

// ---------------------------------------------------------------------------
// CSR SpMM (last layer) fused with h_sum = ego + h1 + h2 + h3
// ---------------------------------------------------------------------------
__global__ void __launch_bounds__(256)
spmm_csr_fused_kernel(const int* __restrict__ row_ptr,
                      const uint2* __restrict__ edges,
                      const float* __restrict__ h2,      // gather source
                      const float* __restrict__ ego,
                      const float* __restrict__ h1,
                      float* __restrict__ h3,
                      float* __restrict__ hsum) {
    int wave = (blockIdx.x * blockDim.x + threadIdx.x) >> 6;
    int lane = threadIdx.x & 63;
    if (wave >= N_NODES) return;
    int start = row_ptr[wave];
    int end   = row_ptr[wave + 1];
    float a0 = 0.f, a1 = 0.f, a2 = 0.f, a3 = 0.f;
    float a4 = 0.f, a5 = 0.f, a6 = 0.f, a7 = 0.f;
    int e = start;
    for (; e + 8 <= end; e += 8) {
        uint2 e0 = edges[e],     e1 = edges[e + 1], e2 = edges[e + 2], e3 = edges[e + 3];
        uint2 e4 = edges[e + 4], e5 = edges[e + 5], e6 = edges[e + 6], e7 = edges[e + 7];
        a0 += __uint_as_float(e0.y) * h2[(int)e0.x * DIM + lane];
        a1 += __uint_as_float(e1.y) * h2[(int)e1.x * DIM + lane];
        a2 += __uint_as_float(e2.y) * h2[(int)e2.x * DIM + lane];
        a3 += __uint_as_float(e3.y) * h2[(int)e3.x * DIM + lane];
        a4 += __uint_as_float(e4.y) * h2[(int)e4.x * DIM + lane];
        a5 += __uint_as_float(e5.y) * h2[(int)e5.x * DIM + lane];
        a6 += __uint_as_float(e6.y) * h2[(int)e6.x * DIM + lane];
        a7 += __uint_as_float(e7.y) * h2[(int)e7.x * DIM + lane];
    }
    for (; e + 4 <= end; e += 4) {
        uint2 e0 = edges[e], e1 = edges[e + 1], e2 = edges[e + 2], e3 = edges[e + 3];
        a0 += __uint_as_float(e0.y) * h2[(int)e0.x * DIM + lane];
        a1 += __uint_as_float(e1.y) * h2[(int)e1.x * DIM + lane];
        a2 += __uint_as_float(e2.y) * h2[(int)e2.x * DIM + lane];
        a3 += __uint_as_float(e3.y) * h2[(int)e3.x * DIM + lane];
    }
    for (; e < end; ++e) {
        uint2 ed = edges[e];
        a0 += __uint_as_float(ed.y) * h2[(int)ed.x * DIM + lane];
    }
    float acc = ((a0 + a1) + (a2 + a3)) + ((a4 + a5) + (a6 + a7));
    int o = wave * DIM + lane;
    h3[o]   = acc;
    hsum[o] = ego[o] + h1[o] + h2[o] + acc;
}

// ---------------------------------------------------------------------------
// Fallback path (used only if ws_size too small for CSR build)
// ---------------------------------------------------------------------------
__global__ void spmm_atomic_kernel(const int* __restrict__ rows,
                                   const int* __restrict__ cols,
                                   const float* __restrict__ vals,
                                   const float* __restrict__ hin,
                                   float* __restrict__ hout) {
    int e = blockIdx.x * 4 + (threadIdx.x >> 6);
    int d = threadIdx.x & 63;
    if (e < N_EDGES) {
        atomicAdd(&hout[rows[e] * DIM + d], vals[e] * hin[cols[e] * DIM + d]);
    }
}

__global__ void zero_f_kernel(float* __restrict__ p, long long n) {
    long long i = (long long)blockIdx.x * blockDim.x + threadIdx.x;
    if (i < n) p[i] = 0.f;
}

__global__ void sum_kernel(const float4* __restrict__ a,
                           const float4* __restrict__ b,
                           const float4* __restrict__ c,
                           const float4* __restrict__ d,
                           float4* __restrict__ out) {
    int i = blockIdx.x * blockDim.x + threadIdx.x;
    if (i < (int)(NF / 4)) {
        float4 x = a[i], y = b[i], z = c[i], w = d[i];
        out[i] = make_float4(x.x + y.x + z.x + w.x,
                             x.y + y.y + z.y + w.y,
                             x.z + y.z + z.z + w.z,
                             x.w + y.w + z.w + w.w);
    }
}

extern "C" void kernel_launch(void* const* d_in, const int* in_sizes, int n_in,
                              void* d_out, int out_size, void* d_ws, size_t ws_size,
                              hipStream_t stream) {
    const float* user = (const float*)d_in[0];
    const float* item = (const float*)d_in[1];
    const float* vals = (const float*)d_in[2];
    const int*   rows = (const int*)d_in[3];
    const int*   cols = (const int*)d_in[4];

    float* out  = (float*)d_out;
    float* hsum = out;
    float* ego  = out + NF;
    float* h1   = out + 2 * NF;
    float* h2   = out + 3 * NF;
    float* h3   = out + 4 * NF;

    const int totF4 = (int)(NF / 4);

    concat_kernel<<<(totF4 + 255) / 256, 256, 0, stream>>>(
        (const float4*)user, (const float4*)item, (float4*)ego);

    // workspace: edges | ovf | row_ptr | bcur | stored | csr_base | ovf_cnt
    size_t need = (size_t)N_EDGES * 8 + (size_t)OVF_CAP * 16
                + ((size_t)N_NODES + 2 + NCB * BCUR_PAD + NCB + NCB + 2 + 16) * 4;

    if (ws_size >= need) {
        uint2* edges    = (uint2*)d_ws;
        uint4* ovf      = (uint4*)(edges + N_EDGES);        // 38.4MB offset, 16B-aligned
        int*   row_ptr  = (int*)(ovf + OVF_CAP);
        int*   bcur     = row_ptr + (N_NODES + 2);
        int*   stored   = bcur + NCB * BCUR_PAD;
        int*   csr_base = stored + NCB;
        int*   ovf_cnt  = csr_base + (NCB + 2);
        // bucket tmp staging lives in the (still-dead) h1/h2 output regions:
        // 256 * 24576 * 8B = 50.3MB <= 76.8MB
        uint2* tmp      = (uint2*)h1;

        build_init_kernel<<<1, 256, 0, stream>>>(bcur, ovf_cnt);
        binA_kernel<<<BINA_BLK, BINA_T, 0, stream>>>(
            rows, cols, vals, bcur, ovf_cnt, ovf, tmp);
        cb_scan_kernel<<<1, NCB, 0, stream>>>(
            bcur, ovf_cnt, ovf, stored, csr_base, row_ptr);
        passB_kernel<<<NCB, PB_T, 0, stream>>>(
            stored, csr_base, ovf_cnt, ovf, tmp, edges, row_ptr);

        const int spmmBlocks = (N_NODES * 64 + 255) / 256;  // 1 wave per row
        spmm_csr_kernel<<<spmmBlocks, 256, 0, stream>>>(row_ptr, edges, ego, h1);
        spmm_csr_kernel<<<spmmBlocks, 256, 0, stream>>>(row_ptr, edges, h1,  h2);
        spmm_csr_fused_kernel<<<spmmBlocks, 256, 0, stream>>>(
            row_ptr, edges, h2, ego, h1, h3, hsum);
    } else {
        const long long nz = 3 * NF;
        zero_f_kernel<<<(int)((nz + 255) / 256), 256, 0, stream>>>(h1, nz);
        const int ablocks = (N_EDGES + 3) / 4;
        spmm_atomic_kernel<<<ablocks, 256, 0, stream>>>(rows, cols, vals, ego, h1);
        spmm_atomic_kernel<<<ablocks, 256, 0, stream>>>(rows, cols, vals, h1,  h2);
        spmm_atomic_kernel<<<ablocks, 256, 0, stream>>>(rows, cols, vals, h2,  h3);
        sum_kernel<<<(totF4 + 255) / 256, 256, 0, stream>>>(
            (const float4*)ego, (const float4*)h1, (const float4*)h2, (const float4*)h3,
            (float4*)hsum);
    }
}

// Round 5
// 873.995 us; speedup vs baseline: 1.6759x; 1.0097x over previous
//
#include <hip/hip_runtime.h>

#define N_USERS 100000
#define N_ITEMS 50000
#define DIM     64
#define N_NODES (N_USERS + N_ITEMS + 1)   /* 150001 */
#define N_EDGES 4800000

static constexpr long long NF = (long long)N_NODES * DIM;   // 9,600,064 floats per tensor

// ------------------- coarse-bucket counting-sort geometry -------------------
#define NCB      256                       /* coarse buckets                  */
#define CB_ROWS  586                       /* rows per bucket: 586*256=150016 */
#define CB_CAP   24576                     /* slots per bucket (mean 18750)   */
#define BCUR_PAD 16                        /* bcur stride in ints (64B lines) */
#define OVF_CAP  65536                     /* overflow list capacity          */
#define CHUNK_E  8192                      /* edges per binA workgroup        */
#define BINA_T   256
#define BINA_BLK ((N_EDGES + CHUNK_E - 1) / CHUNK_E)   /* 586 */
#define PB_T     1024

// ---------------------------------------------------------------------------
// ego = concat(user_emb, item_emb)  (float4-vectorized)
// ---------------------------------------------------------------------------
__global__ void concat_kernel(const float4* __restrict__ user,
                              const float4* __restrict__ item,
                              float4* __restrict__ ego) {
    int i = blockIdx.x * blockDim.x + threadIdx.x;
    const int userF4 = N_USERS * DIM / 4;
    const int totF4  = (int)(NF / 4);
    if (i < userF4)      ego[i] = user[i];
    else if (i < totF4)  ego[i] = item[i - userF4];
}

// ---------------------------------------------------------------------------
// build init: bucket cursors at fixed region bases; clear overflow count
// ---------------------------------------------------------------------------
__global__ void build_init_kernel(int* __restrict__ bcur, int* __restrict__ ovf_cnt) {
    int t = blockIdx.x * blockDim.x + threadIdx.x;
    if (t < NCB) bcur[t * BCUR_PAD] = t * CB_CAP;
    if (t == 0) *ovf_cnt = 0;
}

// ---------------------------------------------------------------------------
// binA: coarse binning. Per 8192-edge chunk: LDS histogram over 256 buckets,
// ONE padded global atomic per (chunk,bucket) to reserve a contiguous range,
// then write packed (row_local<<18 | col, val) into the bucket region.
// ---------------------------------------------------------------------------
__global__ void __launch_bounds__(BINA_T)
binA_kernel(const int* __restrict__ rows, const int* __restrict__ cols,
            const float* __restrict__ vals,
            int* __restrict__ bcur, int* __restrict__ ovf_cnt,
            uint4* __restrict__ ovf, uint2* __restrict__ tmp) {
    __shared__ int hist[NCB];
    __shared__ int gbase[NCB];
    __shared__ int offs[NCB];
    int t = threadIdx.x;
    int base = blockIdx.x * CHUNK_E;
    int nend = N_EDGES - base; if (nend > CHUNK_E) nend = CHUNK_E;
    hist[t] = 0;
    __syncthreads();
    for (int i = t; i < nend; i += BINA_T) {
        int r = rows[base + i];
        atomicAdd(&hist[r / CB_ROWS], 1);
    }
    __syncthreads();
    int h = hist[t];
    gbase[t] = (h > 0) ? atomicAdd(&bcur[t * BCUR_PAD], h) : 0;
    offs[t] = 0;
    __syncthreads();
    for (int i = t; i < nend; i += BINA_T) {
        int e = base + i;
        int r = rows[e];
        unsigned c = (unsigned)cols[e];
        unsigned v = __float_as_uint(vals[e]);
        int b = r / CB_ROWS;
        int o = atomicAdd(&offs[b], 1);
        int p = gbase[b] + o;
        if (p < (b + 1) * CB_CAP) {
            tmp[p] = make_uint2(((unsigned)(r - b * CB_ROWS) << 18) | c, v);
        } else {                                   // statistically impossible
            int ov = atomicAdd(ovf_cnt, 1);
            if (ov < OVF_CAP) ovf[ov] = make_uint4((unsigned)r, c, v, 0u);
        }
    }
}

// ---------------------------------------------------------------------------
// cb_scan: bucket sizes -> exclusive scan -> csr_base.
// ---------------------------------------------------------------------------
__global__ void __launch_bounds__(NCB)
cb_scan_kernel(const int* __restrict__ bcur, const int* __restrict__ ovf_cnt,
               const uint4* __restrict__ ovf,
               int* __restrict__ stored, int* __restrict__ csr_base,
               int* __restrict__ row_ptr) {
    __shared__ int lds[NCB];
    __shared__ int oh[NCB];
    int t = threadIdx.x;
    int st = bcur[t * BCUR_PAD] - t * CB_CAP;
    if (st > CB_CAP) st = CB_CAP;
    stored[t] = st;
    oh[t] = 0;
    __syncthreads();
    int nov = *ovf_cnt; if (nov > OVF_CAP) nov = OVF_CAP;
    for (int i = t; i < nov; i += NCB) atomicAdd(&oh[(int)ovf[i].x / CB_ROWS], 1);
    __syncthreads();
    lds[t] = st + oh[t];
    __syncthreads();
    for (int off = 1; off < NCB; off <<= 1) {
        int x = lds[t];
        int y = (t >= off) ? lds[t - off] : 0;
        __syncthreads();
        lds[t] = x + y;
        __syncthreads();
    }
    csr_base[t] = (t == 0) ? 0 : lds[t - 1];
    if (t == 0) { csr_base[NCB] = lds[NCB - 1]; row_ptr[N_NODES] = N_EDGES; }
}

// ---------------------------------------------------------------------------
// passB: one workgroup per coarse bucket. LDS row-degree count -> LDS scan ->
// row_ptr write -> scatter bucket's tmp interval into final CSR order with
// LDS-only cursors. Zero global atomics.
// ---------------------------------------------------------------------------
__global__ void __launch_bounds__(PB_T)
passB_kernel(const int* __restrict__ stored, const int* __restrict__ csr_base,
             const int* __restrict__ ovf_cnt, const uint4* __restrict__ ovf,
             const uint2* __restrict__ tmp,
             uint2* __restrict__ edges, int* __restrict__ row_ptr) {
    __shared__ int sdeg[PB_T];
    __shared__ int scur[CB_ROWS];
    int b = blockIdx.x, t = threadIdx.x;
    int n = stored[b];
    const uint2* tb = tmp + (long long)b * CB_CAP;
    sdeg[t] = 0;
    __syncthreads();
    for (int i = t; i < n; i += PB_T)
        atomicAdd(&sdeg[tb[i].x >> 18], 1);
    int nov = *ovf_cnt; if (nov > OVF_CAP) nov = OVF_CAP;
    if (nov > 0) {
        for (int i = t; i < nov; i += PB_T) {
            int r = (int)ovf[i].x;
            if (r / CB_ROWS == b) atomicAdd(&sdeg[r - b * CB_ROWS], 1);
        }
    }
    __syncthreads();
    for (int off = 1; off < PB_T; off <<= 1) {       // inclusive scan
        int x = sdeg[t];
        int y = (t >= off) ? sdeg[t - off] : 0;
        __syncthreads();
        sdeg[t] = x + y;
        __syncthreads();
    }
    int cb = csr_base[b];
    int excl = (t == 0) ? 0 : sdeg[t - 1];
    int gr = b * CB_ROWS + t;
    if (t < CB_ROWS && gr < N_NODES) {
        row_ptr[gr] = cb + excl;
        scur[t] = cb + excl;
    }
    __syncthreads();
    for (int i = t; i < n; i += PB_T) {
        uint2 ed = tb[i];
        int p = atomicAdd(&scur[ed.x >> 18], 1);
        edges[p] = make_uint2(ed.x & 0x3FFFFu, ed.y);
    }
    if (nov > 0 && t == 0) {
        for (int i = 0; i < nov; ++i) {
            int r = (int)ovf[i].x;
            if (r / CB_ROWS == b) {
                int p = atomicAdd(&scur[r - b * CB_ROWS], 1);
                edges[p] = make_uint2(ovf[i].y, ovf[i].z);
            }
        }
    }
}

// ---------------------------------------------------------------------------
// float4-lane CSR SpMM: one wave per row. lane = (g, dq): g = lane>>4 picks
// one of 4 edges per step, dq = lane&15 owns dim quad [4dq, 4dq+4).
// One gather instruction fetches 4 edges x 256B = 1KB (vs 256B before);
// 4 chains x 4 edges = 16 edges in flight per wave, 4x fewer VMEM instrs.
// Cross-group reduce: shfl_xor ^16, ^32 at row end.
// ---------------------------------------------------------------------------
__device__ __forceinline__ void fma4(float4& a, float w, float4 v) {
    a.x += w * v.x; a.y += w * v.y; a.z += w * v.z; a.w += w * v.w;
}

__global__ void __launch_bounds__(256)
spmm_csr_kernel(const int* __restrict__ row_ptr,
                const uint2* __restrict__ edges,
                const float* __restrict__ hin,
                float* __restrict__ hout) {
    int wave = (blockIdx.x * blockDim.x + threadIdx.x) >> 6;
    int lane = threadIdx.x & 63;
    if (wave >= N_NODES) return;
    int g  = lane >> 4;
    int dq = lane & 15;
    const float4* __restrict__ hin4 = (const float4*)hin;
    int start = row_ptr[wave];
    int end   = row_ptr[wave + 1];
    float4 a0 = make_float4(0.f, 0.f, 0.f, 0.f);
    float4 a1 = a0, a2 = a0, a3 = a0;
    int e = start;
    for (; e + 16 <= end; e += 16) {
        uint2 e0 = edges[e + g];
        uint2 e1 = edges[e + 4 + g];
        uint2 e2 = edges[e + 8 + g];
        uint2 e3 = edges[e + 12 + g];
        float4 v0 = hin4[(int)e0.x * 16 + dq];
        float4 v1 = hin4[(int)e1.x * 16 + dq];
        float4 v2 = hin4[(int)e2.x * 16 + dq];
        float4 v3 = hin4[(int)e3.x * 16 + dq];
        fma4(a0, __uint_as_float(e0.y), v0);
        fma4(a1, __uint_as_float(e1.y), v1);
        fma4(a2, __uint_as_float(e2.y), v2);
        fma4(a3, __uint_as_float(e3.y), v3);
    }
    for (; e < end; e += 4) {
        int ei = e + g;                               // uniform per 16-lane group
        uint2 ed = (ei < end) ? edges[ei] : make_uint2(0u, 0u);
        float4 v = hin4[(int)ed.x * 16 + dq];         // col 0 read when guarded
        fma4(a0, __uint_as_float(ed.y), v);           // w = 0 -> no contribution
    }
    float4 s = make_float4((a0.x + a1.x) + (a2.x + a3.x),
                           (a0.y + a1.y) + (a2.y + a3.y),
                           (a0.z + a1.z) + (a2.z + a3.z),
                           (a0.w + a1.w) + (a2.w + a3.w));
    s.x += __shfl_xor(s.x, 16); s.y += __shfl_xor(s.y, 16);
    s.z += __shfl_xor(s.z, 16); s.w += __shfl_xor(s.w, 16);
    s.x += __shfl_xor(s.x, 32); s.y += __shfl_xor(s.y, 32);
    s.z += __shfl_xor(s.z, 32); s.w += __shfl_xor(s.w, 32);
    if (g == 0) ((float4*)hout)[wave * 16 + dq] = s;
}

// ---------------------------------------------------------------------------
// float4-lane CSR SpMM (last layer) fused with h_sum = ego + h1 + h2 + h3
// ---------------------------------------------------------------------------
__global__ void __launch_bounds__(256)
spmm_csr_fused_kernel(const int* __restrict__ row_ptr,
                      const uint2* __restrict__ edges,
                      const float* __restrict__ h2,      // gather source
                      const float* __restrict__ ego,
                      const float* __restrict__ h1,
                      float* __restrict__ h3,
                      float* __restrict__ hsum) {
    int wave = (blockIdx.x * blockDim.x + threadIdx.x) >> 6;
    int lane = threadIdx.x & 63;
    if (wave >= N_NODES) return;
    int g  = lane >> 4;
    int dq = lane & 15;
    const float4* __restrict__ h24 = (const float4*)h2;
    int start = row_ptr[wave];
    int end   = row_ptr[wave + 1];
    float4 a0 = make_float4(0.f, 0.f, 0.f, 0.f);
    float4 a1 = a0, a2 = a0, a3 = a0;
    int e = start;
    for (; e + 16 <= end; e += 16) {
        uint2 e0 = edges[e + g];
        uint2 e1 = edges[e + 4 + g];
        uint2 e2 = edges[e + 8 + g];
        uint2 e3 = edges[e + 12 + g];
        float4 v0 = h24[(int)e0.x * 16 + dq];
        float4 v1 = h24[(int)e1.x * 16 + dq];
        float4 v2 = h24[(int)e2.x * 16 + dq];
        float4 v3 = h24[(int)e3.x * 16 + dq];
        fma4(a0, __uint_as_float(e0.y), v0);
        fma4(a1, __uint_as_float(e1.y), v1);
        fma4(a2, __uint_as_float(e2.y), v2);
        fma4(a3, __uint_as_float(e3.y), v3);
    }
    for (; e < end; e += 4) {
        int ei = e + g;
        uint2 ed = (ei < end) ? edges[ei] : make_uint2(0u, 0u);
        float4 v = h24[(int)ed.x * 16 + dq];
        fma4(a0, __uint_as_float(ed.y), v);
    }
    float4 s = make_float4((a0.x + a1.x) + (a2.x + a3.x),
                           (a0.y + a1.y) + (a2.y + a3.y),
                           (a0.z + a1.z) + (a2.z + a3.z),
                           (a0.w + a1.w) + (a2.w + a3.w));
    s.x += __shfl_xor(s.x, 16); s.y += __shfl_xor(s.y, 16);
    s.z += __shfl_xor(s.z, 16); s.w += __shfl_xor(s.w, 16);
    s.x += __shfl_xor(s.x, 32); s.y += __shfl_xor(s.y, 32);
    s.z += __shfl_xor(s.z, 32); s.w += __shfl_xor(s.w, 32);
    if (g == 0) {
        int o = wave * 16 + dq;
        float4 E  = ((const float4*)ego)[o];
        float4 H1 = ((const float4*)h1)[o];
        float4 H2 = ((const float4*)h2)[o];
        ((float4*)h3)[o] = s;
        ((float4*)hsum)[o] = make_float4(E.x + H1.x + H2.x + s.x,
                                         E.y + H1.y + H2.y + s.y,
                                         E.z + H1.z + H2.z + s.z,
                                         E.w + H1.w + H2.w + s.w);
    }
}

// ---------------------------------------------------------------------------
// Fallback path (used only if ws_size too small for CSR build)
// ---------------------------------------------------------------------------
__global__ void spmm_atomic_kernel(const int* __restrict__ rows,
                                   const int* __restrict__ cols,
                                   const float* __restrict__ vals,
                                   const float* __restrict__ hin,
                                   float* __restrict__ hout) {
    int e = blockIdx.x * 4 + (threadIdx.x >> 6);
    int d = threadIdx.x & 63;
    if (e < N_EDGES) {
        atomicAdd(&hout[rows[e] * DIM + d], vals[e] * hin[cols[e] * DIM + d]);
    }
}

__global__ void zero_f_kernel(float* __restrict__ p, long long n) {
    long long i = (long long)blockIdx.x * blockDim.x + threadIdx.x;
    if (i < n) p[i] = 0.f;
}

__global__ void sum_kernel(const float4* __restrict__ a,
                           const float4* __restrict__ b,
                           const float4* __restrict__ c,
                           const float4* __restrict__ d,
                           float4* __restrict__ out) {
    int i = blockIdx.x * blockDim.x + threadIdx.x;
    if (i < (int)(NF / 4)) {
        float4 x = a[i], y = b[i], z = c[i], w = d[i];
        out[i] = make_float4(x.x + y.x + z.x + w.x,
                             x.y + y.y + z.y + w.y,
                             x.z + y.z + z.z + w.z,
                             x.w + y.w + z.w + w.w);
    }
}

extern "C" void kernel_launch(void* const* d_in, const int* in_sizes, int n_in,
                              void* d_out, int out_size, void* d_ws, size_t ws_size,
                              hipStream_t stream) {
    const float* user = (const float*)d_in[0];
    const float* item = (const float*)d_in[1];
    const float* vals = (const float*)d_in[2];
    const int*   rows = (const int*)d_in[3];
    const int*   cols = (const int*)d_in[4];

    float* out  = (float*)d_out;
    float* hsum = out;
    float* ego  = out + NF;
    float* h1   = out + 2 * NF;
    float* h2   = out + 3 * NF;
    float* h3   = out + 4 * NF;

    const int totF4 = (int)(NF / 4);

    concat_kernel<<<(totF4 + 255) / 256, 256, 0, stream>>>(
        (const float4*)user, (const float4*)item, (float4*)ego);

    // workspace: edges | ovf | row_ptr | bcur | stored | csr_base | ovf_cnt
    size_t need = (size_t)N_EDGES * 8 + (size_t)OVF_CAP * 16
                + ((size_t)N_NODES + 2 + NCB * BCUR_PAD + NCB + NCB + 2 + 16) * 4;

    if (ws_size >= need) {
        uint2* edges    = (uint2*)d_ws;
        uint4* ovf      = (uint4*)(edges + N_EDGES);        // 38.4MB offset, 16B-aligned
        int*   row_ptr  = (int*)(ovf + OVF_CAP);
        int*   bcur     = row_ptr + (N_NODES + 2);
        int*   stored   = bcur + NCB * BCUR_PAD;
        int*   csr_base = stored + NCB;
        int*   ovf_cnt  = csr_base + (NCB + 2);
        // bucket tmp staging lives in the (still-dead) h1/h2 output regions:
        // 256 * 24576 * 8B = 50.3MB <= 76.8MB
        uint2* tmp      = (uint2*)h1;

        build_init_kernel<<<1, 256, 0, stream>>>(bcur, ovf_cnt);
        binA_kernel<<<BINA_BLK, BINA_T, 0, stream>>>(
            rows, cols, vals, bcur, ovf_cnt, ovf, tmp);
        cb_scan_kernel<<<1, NCB, 0, stream>>>(
            bcur, ovf_cnt, ovf, stored, csr_base, row_ptr);
        passB_kernel<<<NCB, PB_T, 0, stream>>>(
            stored, csr_base, ovf_cnt, ovf, tmp, edges, row_ptr);

        const int spmmBlocks = (N_NODES * 64 + 255) / 256;  // 1 wave per row
        spmm_csr_kernel<<<spmmBlocks, 256, 0, stream>>>(row_ptr, edges, ego, h1);
        spmm_csr_kernel<<<spmmBlocks, 256, 0, stream>>>(row_ptr, edges, h1,  h2);
        spmm_csr_fused_kernel<<<spmmBlocks, 256, 0, stream>>>(
            row_ptr, edges, h2, ego, h1, h3, hsum);
    } else {
        const long long nz = 3 * NF;
        zero_f_kernel<<<(int)((nz + 255) / 256), 256, 0, stream>>>(h1, nz);
        const int ablocks = (N_EDGES + 3) / 4;
        spmm_atomic_kernel<<<ablocks, 256, 0, stream>>>(rows, cols, vals, ego, h1);
        spmm_atomic_kernel<<<ablocks, 256, 0, stream>>>(rows, cols, vals, h1,  h2);
        spmm_atomic_kernel<<<ablocks, 256, 0, stream>>>(rows, cols, vals, h2,  h3);
        sum_kernel<<<(totF4 + 255) / 256, 256, 0, stream>>>(
            (const float4*)ego, (const float4*)h1, (const float4*)h2, (const float4*)h3,
            (float4*)hsum);
    }
}